// Round 1
// 501.254 us; speedup vs baseline: 1.0032x; 1.0032x over previous
//
#include <hip/hip_runtime.h>
#include <math.h>

#define BATCH  8192
#define D_IN   592
#define FBANKS 8
#define P1     147   // pool1 output length
#define P2     36    // pool2 output length
#define P1PAD  152   // padded row (16B-multiple stride, room for b128 over-read)
#define NW     4     // waves (rows) per block

// Wave-synchronous ordering: CDNA waves are lockstep (one PC + exec mask) and
// DS ops complete in program order per wave, so producer->consumer through
// per-wave LDS scratch needs only a compiler reordering fence, not s_barrier.
#define WAVE_SYNC() do { __builtin_amdgcn_wave_barrier(); asm volatile("" ::: "memory"); } while (0)

// All wave-uniform weight reads go straight to global memory: uniform address
// => compiler emits s_load into SGPRs (scalar cache), freeing ~21 VGPRs and
// removing the LDS staging phase + the block-wide __syncthreads entirely.
// l1w/l2w per-lane rows stay as vector loads (L1-resident: 23KB+6.4KB total).

__global__ __launch_bounds__(256, 6) void fb_kernel(
    const float* __restrict__ x,
    const float* __restrict__ c1w, const float* __restrict__ c1b,
    const float* __restrict__ c2w, const float* __restrict__ c2b,
    const float* __restrict__ l1w, const float* __restrict__ l1b,
    const float* __restrict__ l2w, const float* __restrict__ l2b,
    const float* __restrict__ l3w, const float* __restrict__ l3b,
    float* __restrict__ outH, float* __restrict__ outXF,
    float* __restrict__ outXS, float* __restrict__ outF0)
{
    // ---- per-wave scratch only (no cross-wave sharing -> no __syncthreads) ----
    __shared__ __align__(16) float s_xa[NW][D_IN];
    __shared__ __align__(16) float s_p1[NW][3][P1PAD];
    __shared__ __align__(16) float s_p2[NW][40];
    __shared__ __align__(16) float s_l1o[NW][20];
    // LDS/block = 4*(2368+1824+160+80) = 17728 B (was 26.3 KB)

    const int tid  = threadIdx.x;
    const int wave = tid >> 6;
    const int lane = tid & 63;
    const int row  = blockIdx.x * NW + wave;

    float* xa = s_xa[wave];
    {
        const float* xrow = x + (size_t)row * D_IN;
        for (int i = lane; i < 148; i += 64) {           // 148 float4 = 592 floats
            *(float4*)&xa[4 * i] = *(const float4*)&xrow[4 * i];
        }
    }
    WAVE_SYNC();

    // Gaussian: H = exp(-d^2/(2w^2)) = exp2(d^2 * negc2), w=5
    const float negc2 = -0.028853900817779268f;   // -log2(e)/50

    for (int bank = 0; bank < FBANKS; ++bank) {
        // ---- wave-uniform weights -> SGPRs (s_load, scalar cache) ----
        float w1[3][3], b1[3], w2[3][3];
        #pragma unroll
        for (int c = 0; c < 3; ++c) {
            b1[c] = c1b[bank * 3 + c];
            #pragma unroll
            for (int k = 0; k < 3; ++k) {
                w1[c][k] = c1w[bank * 9 + c * 3 + k];
                w2[c][k] = c2w[bank * 9 + c * 3 + k];
            }
        }
        const float b2 = c2b[bank];

        // ---- conv1(k3,s2)+maxpool(3,2)+relu: pooled p covers x[4p..4p+6] ----
        for (int p = lane; p < P1; p += 64) {
            float4 a = *(const float4*)&xa[4 * p];       // 4p..4p+3
            float4 b = *(const float4*)&xa[4 * p + 4];   // 4p+4..4p+7 (max 591)
            float xv0 = a.x, xv1 = a.y, xv2 = a.z, xv3 = a.w;
            float xv4 = b.x, xv5 = b.y, xv6 = b.z;
            #pragma unroll
            for (int c = 0; c < 3; ++c) {
                float v0 = w1[c][0] * xv0 + w1[c][1] * xv1 + w1[c][2] * xv2;
                float v1 = w1[c][0] * xv2 + w1[c][1] * xv3 + w1[c][2] * xv4;
                float v2 = w1[c][0] * xv4 + w1[c][1] * xv5 + w1[c][2] * xv6;
                float m  = fmaxf(fmaxf(v0, v1), v2) + b1[c];
                s_p1[wave][c][p] = fmaxf(m, 0.0f);
            }
        }
        WAVE_SYNC();

        // ---- conv2(3ch->1,k3,s2)+maxpool(3,2)+relu: q covers p1[c][4q..4q+6] ----
        if (lane < P2) {
            const int q = lane;
            float acc0 = b2, acc1 = b2, acc2 = b2;
            #pragma unroll
            for (int c = 0; c < 3; ++c) {
                const float* r = s_p1[wave][c];
                float4 a = *(const float4*)&r[4 * q];
                float4 b = *(const float4*)&r[4 * q + 4];
                float v0 = a.x, v1 = a.y, v2 = a.z, v3 = a.w, v4 = b.x, v5 = b.y, v6 = b.z;
                acc0 += w2[c][0] * v0 + w2[c][1] * v1 + w2[c][2] * v2;
                acc1 += w2[c][0] * v2 + w2[c][1] * v3 + w2[c][2] * v4;
                acc2 += w2[c][0] * v4 + w2[c][1] * v5 + w2[c][2] * v6;
            }
            float mm = fmaxf(fmaxf(acc0, acc1), acc2);
            s_p2[wave][q] = fmaxf(mm, 0.0f);
        }
        WAVE_SYNC();

        // ---- lin1: 36 -> 20, relu (weights straight from global: L1-resident) ----
        if (lane < 20) {
            const float4* wr = (const float4*)(l1w + bank * 720 + lane * 36);
            float acc = l1b[bank * 20 + lane];
            #pragma unroll
            for (int k = 0; k < 9; ++k) {
                float4 w = wr[k];
                float4 v = *(const float4*)&s_p2[wave][4 * k];   // broadcast read
                acc += w.x * v.x + w.y * v.y + w.z * v.z + w.w * v.w;
            }
            s_l1o[wave][lane] = fmaxf(acc, 0.0f);
        }
        WAVE_SYNC();

        // ---- lin2 (20->10, relu) fused with lin3 (10->1) via shuffle reduce ----
        float part = 0.0f;
        if (lane < 10) {
            const float4* wr = (const float4*)(l2w + bank * 200 + lane * 20);
            float acc = l2b[bank * 10 + lane];
            #pragma unroll
            for (int k = 0; k < 5; ++k) {
                float4 w = wr[k];
                float4 v = *(const float4*)&s_l1o[wave][4 * k];  // broadcast read
                acc += w.x * v.x + w.y * v.y + w.z * v.z + w.w * v.w;
            }
            part = fmaxf(acc, 0.0f) * l3w[bank * 10 + lane];     // fold lin3 weight
        }
        // sum over lanes 0..9 (others contribute 0); xor-tree within 16-lane group
        part += __shfl_xor(part, 1);
        part += __shfl_xor(part, 2);
        part += __shfl_xor(part, 4);
        part += __shfl_xor(part, 8);
        // lane 0 holds the full dot; broadcast via readfirstlane (exec is full here)
        float acc3 = __uint_as_float(__builtin_amdgcn_readfirstlane(__float_as_uint(part)))
                   + l3b[bank];
        float sig  = 1.0f / (1.0f + __expf(-acc3));
        float f0v  = (float)D_IN * sig;
        if (lane == 0) outF0[(size_t)bank * BATCH + row] = f0v;

        // ---- Gaussian filter + vectorized outputs + state update ----
        const size_t base = ((size_t)bank * BATCH + row) * D_IN;
        for (int i = lane; i < 148; i += 64) {
            float4 xv = *(const float4*)&xa[4 * i];
            float d0 = (float)(4 * i) - f0v;
            float d1 = d0 + 1.0f;
            float d2 = d0 + 2.0f;
            float d3 = d0 + 3.0f;
            float4 Hv, xf, xn;
            Hv.x = __builtin_amdgcn_exp2f(d0 * d0 * negc2);
            Hv.y = __builtin_amdgcn_exp2f(d1 * d1 * negc2);
            Hv.z = __builtin_amdgcn_exp2f(d2 * d2 * negc2);
            Hv.w = __builtin_amdgcn_exp2f(d3 * d3 * negc2);
            xf.x = xv.x * Hv.x;  xf.y = xv.y * Hv.y;
            xf.z = xv.z * Hv.z;  xf.w = xv.w * Hv.w;
            xn.x = xv.x - xf.x;  xn.y = xv.y - xf.y;
            xn.z = xv.z - xf.z;  xn.w = xv.w - xf.w;
            *(float4*)&outXS[base + 4 * i] = xv;
            *(float4*)&outH [base + 4 * i] = Hv;
            *(float4*)&outXF[base + 4 * i] = xf;
            if (bank != FBANKS - 1)                      // last bank: xa is dead
                *(float4*)&xa[4 * i] = xn;
        }
        WAVE_SYNC();
    }
}

extern "C" void kernel_launch(void* const* d_in, const int* in_sizes, int n_in,
                              void* d_out, int out_size, void* d_ws, size_t ws_size,
                              hipStream_t stream) {
    const float* x   = (const float*)d_in[0];
    const float* c1w = (const float*)d_in[1];
    const float* c1b = (const float*)d_in[2];
    const float* c2w = (const float*)d_in[3];
    const float* c2b = (const float*)d_in[4];
    const float* l1w = (const float*)d_in[5];
    const float* l1b = (const float*)d_in[6];
    const float* l2w = (const float*)d_in[7];
    const float* l2b = (const float*)d_in[8];
    const float* l3w = (const float*)d_in[9];
    const float* l3b = (const float*)d_in[10];

    float* out = (float*)d_out;
    const size_t plane = (size_t)FBANKS * BATCH * D_IN;
    float* outH  = out;
    float* outXF = out + plane;
    float* outXS = out + 2 * plane;
    float* outF0 = out + 3 * plane;

    dim3 grid(BATCH / NW);
    dim3 block(256);
    fb_kernel<<<grid, block, 0, stream>>>(x, c1w, c1b, c2w, c2b,
                                          l1w, l1b, l2w, l2b, l3w, l3b,
                                          outH, outXF, outXS, outF0);
}